// Round 5
// baseline (102.957 us; speedup 1.0000x reference)
//
#include <hip/hip_runtime.h>

typedef unsigned int uint32;

namespace {
constexpr int CCH = 256;   // channels
constexpr int OUT = 7;     // output size
constexpr int S   = 14;    // OUT * SAMPLE_NUM
constexpr int NUM_ROIS = 1024;

constexpr int H0 = 200, W0 = 304;
constexpr int H1 = 100, W1 = 152;
constexpr int H2 = 50,  W2 = 76;
constexpr int H3 = 25,  W3 = 38;

// transposed bf16 NHWC level sizes (in ushorts)
constexpr size_t US0 = (size_t)2 * H0 * W0 * CCH;
constexpr size_t US1 = (size_t)2 * H1 * W1 * CCH;
constexpr size_t US2 = (size_t)2 * H2 * W2 * CCH;
constexpr size_t US3 = (size_t)2 * H3 * W3 * CCH;

// fused transpose tile counts (32-x tiles per (y,b))
constexpr int T0 = 10 * H0 * 2;   // 4000
constexpr int T1 = 5  * H1 * 2;   // 1000
constexpr int T2 = 3  * H2 * 2;   // 300
constexpr int T3 = 2  * H3 * 2;   // 100

constexpr int LDSW = 130;  // LDS row stride in 32-bit words (260 ushorts)
}

__device__ __forceinline__ unsigned short f2bf(float f) {
    uint32 u = __float_as_uint(f);
    u += 0x7fffu + ((u >> 16) & 1u);          // round-to-nearest-even
    return (unsigned short)(u >> 16);
}
__device__ __forceinline__ float blo(uint32 u) { return __uint_as_float(u << 16); }
__device__ __forceinline__ float bhi(uint32 u) { return __uint_as_float(u & 0xffff0000u); }

// ---------------- fused NCHW fp32 -> NHWC bf16 transpose (all levels) -------
// Tile: 32 x-positions x 256 channels. LDS layout: [x][c] ushorts, row stride
// 260 ushorts (130 words). Phase A: register-staged float4 loads (8 in
// flight), channel-pair packed b32 LDS writes (2 lanes/bank = conflict-free).
// Phase B: 2x ds_read_b64 -> one dwordx4 global store per x row chunk.
__global__ __launch_bounds__(256) void transpose_bf16(
    const float* __restrict__ f0, const float* __restrict__ f1,
    const float* __restrict__ f2, const float* __restrict__ f3,
    unsigned short* __restrict__ o0, unsigned short* __restrict__ o1,
    unsigned short* __restrict__ o2, unsigned short* __restrict__ o3)
{
    __shared__ __align__(16) uint32 lds[32 * LDSW];
    int r = blockIdx.x;
    const float* in; unsigned short* op; int H, W, TX;
    if (r < T0)           {            in = f0; op = o0; H = H0; W = W0; TX = 10; }
    else if (r < T0+T1)   { r -= T0;   in = f1; op = o1; H = H1; W = W1; TX = 5; }
    else if (r < T0+T1+T2){ r -= T0+T1; in = f2; op = o2; H = H2; W = W2; TX = 3; }
    else                  { r -= T0+T1+T2; in = f3; op = o3; H = H3; W = W3; TX = 2; }
    const int tx = r % TX; r /= TX;
    const int y = r % H;
    const int b = r / H;
    const int x0 = tx * 32;
    const int t = threadIdx.x;

    // ---- Phase A ----
    const int xq = t & 7;          // x quad (4 floats)
    const int cp = t >> 3;         // channel pair index 0..31 (c = 2cp + 64i)
    const int x  = x0 + 4 * xq;

    float4 va[4], vb[4];           // channel c and c+1, i = 0..3
    {
        const bool w4 = ((W & 3) == 0) && (x + 3 < W);
        const float* s0 = in + (((size_t)(b * CCH + 2 * cp) * H + y) * W + x);
        const size_t cstep = (size_t)64 * H * W;
        if (w4) {
            #pragma unroll
            for (int i = 0; i < 4; ++i) {
                const float* p = s0 + i * cstep;
                va[i] = *reinterpret_cast<const float4*>(p);
                vb[i] = *reinterpret_cast<const float4*>(p + (size_t)H * W);
            }
        } else {
            #pragma unroll
            for (int i = 0; i < 4; ++i) {
                const float* p = s0 + i * cstep;
                const float* q = p + (size_t)H * W;
                va[i] = make_float4(0.f, 0.f, 0.f, 0.f);
                vb[i] = make_float4(0.f, 0.f, 0.f, 0.f);
                if (x     < W) { va[i].x = p[0]; vb[i].x = q[0]; }
                if (x + 1 < W) { va[i].y = p[1]; vb[i].y = q[1]; }
                if (x + 2 < W) { va[i].z = p[2]; vb[i].z = q[2]; }
                if (x + 3 < W) { va[i].w = p[3]; vb[i].w = q[3]; }
            }
        }
    }
    #pragma unroll
    for (int i = 0; i < 4; ++i) {
        const uint32 u0 = (uint32)f2bf(va[i].x) | ((uint32)f2bf(vb[i].x) << 16);
        const uint32 u1 = (uint32)f2bf(va[i].y) | ((uint32)f2bf(vb[i].y) << 16);
        const uint32 u2 = (uint32)f2bf(va[i].z) | ((uint32)f2bf(vb[i].z) << 16);
        const uint32 u3 = (uint32)f2bf(va[i].w) | ((uint32)f2bf(vb[i].w) << 16);
        const int wbase = cp + 32 * i;
        lds[(4 * xq + 0) * LDSW + wbase] = u0;
        lds[(4 * xq + 1) * LDSW + wbase] = u1;
        lds[(4 * xq + 2) * LDSW + wbase] = u2;
        lds[(4 * xq + 3) * LDSW + wbase] = u3;
    }
    __syncthreads();

    // ---- Phase B ----
    {
        const int cg  = t & 31;        // channel group of 8 (4 words)
        const int xr0 = t >> 5;        // 0..7
        uint2 ra[4], rb[4];
        #pragma unroll
        for (int i = 0; i < 4; ++i) {
            const int xr = xr0 + 8 * i;
            ra[i] = *reinterpret_cast<const uint2*>(&lds[xr * LDSW + 4 * cg]);
            rb[i] = *reinterpret_cast<const uint2*>(&lds[xr * LDSW + 4 * cg + 2]);
        }
        #pragma unroll
        for (int i = 0; i < 4; ++i) {
            const int xr = xr0 + 8 * i;
            const int xo = x0 + xr;
            if (xo < W) {
                uint4 v = make_uint4(ra[i].x, ra[i].y, rb[i].x, rb[i].y);
                *reinterpret_cast<uint4*>(
                    op + (((size_t)b * H + y) * W + xo) * CCH + 8 * cg) = v;
            }
        }
    }
}

// ---------------- gather from NHWC bf16 -------------------------------------
__global__ __launch_bounds__(256) void roi_gather_bf16(
    const unsigned short* __restrict__ w0, const unsigned short* __restrict__ w1,
    const unsigned short* __restrict__ w2, const unsigned short* __restrict__ w3,
    const float* __restrict__ rois, float* __restrict__ out)
{
    const int k = blockIdx.x;
    const int t = threadIdx.x;

    __shared__ float s_wlo[2][S];
    __shared__ float s_whi[2][S];
    __shared__ int   s_olo[2][S];   // offsets in uint2 units (y: W*64, x: 64)
    __shared__ int   s_ohi[2][S];
    __shared__ __align__(16) float s_out[25 * 260];

    const float rb  = rois[k*5+0];
    const float rx1 = rois[k*5+1];
    const float ry1 = rois[k*5+2];
    const float rx2 = rois[k*5+3];
    const float ry2 = rois[k*5+4];

    const float sc = sqrtf((rx2 - rx1 + 1.0f) * (ry2 - ry1 + 1.0f));
    int lvl = (int)floorf(log2f(sc * (1.0f/56.0f) + 1e-6f));
    lvl = lvl < 0 ? 0 : (lvl > 3 ? 3 : lvl);

    const unsigned short* fp; int H, W; float sp;
    if (lvl == 0)      { fp = w0; H = H0; W = W0; sp = 0.25f;    }
    else if (lvl == 1) { fp = w1; H = H1; W = W1; sp = 0.125f;   }
    else if (lvl == 2) { fp = w2; H = H2; W = W2; sp = 0.0625f;  }
    else               { fp = w3; H = H3; W = W3; sp = 0.03125f; }

    if (t < 2*S) {
        const int axis = (t >= S) ? 1 : 0;     // 0=y, 1=x
        const int i = axis ? (t - S) : t;
        const float lo = (axis ? rx1 : ry1) * sp;
        const float hi = (axis ? rx2 : ry2) * sp;
        const int dim  = axis ? W : H;
        const float len = fmaxf(hi - lo, 1.0f);
        const float bin = len * (1.0f / (float)S);
        const float v = lo + ((float)i + 0.5f) * bin;
        const bool valid = (v >= -1.0f) && (v <= (float)dim);
        float vc = fmaxf(v, 0.0f);
        int l = (int)floorf(vc);
        if (l >= dim - 1) { vc = (float)(dim - 1); l = dim - 1; }
        const int h = min(l + 1, dim - 1);
        const float frac = vc - (float)l;
        float wlo = 1.0f - frac;
        float whi = frac;
        if (!valid) { wlo = 0.0f; whi = 0.0f; }
        const int mul = axis ? 64 : W * 64;    // uint2 units
        s_wlo[axis][i] = wlo;
        s_whi[axis][i] = whi;
        s_olo[axis][i] = l * mul;
        s_ohi[axis][i] = h * mul;
    }
    __syncthreads();

    const int b = (int)rb;
    const int lane = t & 63;
    const int wv   = t >> 6;
    const uint2* __restrict__ base =
        reinterpret_cast<const uint2*>(fp) + (size_t)b * H * W * 64 + lane;
    float* __restrict__ ob = out + (size_t)k * CCH * (OUT * OUT);

    #pragma unroll
    for (int hf = 0; hf < 2; ++hf) {
        const int bb = hf ? 25 : 0;
        const int ne = hf ? 24 : 25;

        for (int bl = wv; bl < ne; bl += 4) {
            const int bin = bb + bl;
            const int oh = bin / 7;
            const int ow = bin - oh * 7;
            const int sy0 = oh * 2, sx0 = ow * 2;
            float a0 = 0.f, a1 = 0.f, a2 = 0.f, a3 = 0.f;
            #pragma unroll
            for (int dy = 0; dy < 2; ++dy) {
                const float hy = s_wlo[0][sy0 + dy];
                const float ly = s_whi[0][sy0 + dy];
                const int oyl = s_olo[0][sy0 + dy];
                const int oyh = s_ohi[0][sy0 + dy];
                #pragma unroll
                for (int dx = 0; dx < 2; ++dx) {
                    const float hx = s_wlo[1][sx0 + dx];
                    const float lx = s_whi[1][sx0 + dx];
                    const int oxl = s_olo[1][sx0 + dx];
                    const int oxh = s_ohi[1][sx0 + dx];
                    const uint2 qll = base[oyl + oxl];
                    const uint2 qlh = base[oyl + oxh];
                    const uint2 qhl = base[oyh + oxl];
                    const uint2 qhh = base[oyh + oxh];
                    const float wll = hy * hx, wlh = hy * lx;
                    const float whl = ly * hx, whh = ly * lx;
                    a0 += wll*blo(qll.x) + wlh*blo(qlh.x) + whl*blo(qhl.x) + whh*blo(qhh.x);
                    a1 += wll*bhi(qll.x) + wlh*bhi(qlh.x) + whl*bhi(qhl.x) + whh*bhi(qhh.x);
                    a2 += wll*blo(qll.y) + wlh*blo(qlh.y) + whl*blo(qhl.y) + whh*blo(qhh.y);
                    a3 += wll*bhi(qll.y) + wlh*bhi(qlh.y) + whl*bhi(qhl.y) + whh*bhi(qhh.y);
                }
            }
            float4 res = make_float4(a0*0.25f, a1*0.25f, a2*0.25f, a3*0.25f);
            *reinterpret_cast<float4*>(&s_out[bl * 260 + 4 * lane]) = res;
        }
        __syncthreads();

        // dump: 256*ne elements, c-major flat index for near-coalesced stores
        #pragma unroll 1
        for (int j = 0; j < ne; ++j) {
            const int f = t + j * 256;
            const int c = f / ne;
            const int bl = f - c * ne;
            ob[c * (OUT*OUT) + bb + bl] = s_out[bl * 260 + c];
        }
        __syncthreads();
    }
}

// ---------------- fallback (direct NCHW fp32) if ws too small ---------------
__global__ __launch_bounds__(256) void roi_extract_direct(
    const float* __restrict__ f0, const float* __restrict__ f1,
    const float* __restrict__ f2, const float* __restrict__ f3,
    const float* __restrict__ rois, float* __restrict__ out)
{
    const int k = blockIdx.x;
    const int t = threadIdx.x;

    __shared__ float s_wlo[2][S];
    __shared__ float s_whi[2][S];
    __shared__ int   s_olo[2][S];
    __shared__ int   s_ohi[2][S];

    const float rb  = rois[k*5+0];
    const float rx1 = rois[k*5+1];
    const float ry1 = rois[k*5+2];
    const float rx2 = rois[k*5+3];
    const float ry2 = rois[k*5+4];

    const float sc = sqrtf((rx2 - rx1 + 1.0f) * (ry2 - ry1 + 1.0f));
    int lvl = (int)floorf(log2f(sc * (1.0f/56.0f) + 1e-6f));
    lvl = lvl < 0 ? 0 : (lvl > 3 ? 3 : lvl);

    const float* fp; int H, W; float sp;
    if (lvl == 0)      { fp = f0; H = H0; W = W0; sp = 0.25f;    }
    else if (lvl == 1) { fp = f1; H = H1; W = W1; sp = 0.125f;   }
    else if (lvl == 2) { fp = f2; H = H2; W = W2; sp = 0.0625f;  }
    else               { fp = f3; H = H3; W = W3; sp = 0.03125f; }

    if (t < 2*S) {
        const int axis = (t >= S) ? 1 : 0;
        const int i = axis ? (t - S) : t;
        const float lo = (axis ? rx1 : ry1) * sp;
        const float hi = (axis ? rx2 : ry2) * sp;
        const int dim  = axis ? W : H;
        const float len = fmaxf(hi - lo, 1.0f);
        const float bin = len * (1.0f / (float)S);
        const float v = lo + ((float)i + 0.5f) * bin;
        const bool valid = (v >= -1.0f) && (v <= (float)dim);
        float vc = fmaxf(v, 0.0f);
        int l = (int)floorf(vc);
        if (l >= dim - 1) { vc = (float)(dim - 1); l = dim - 1; }
        const int h = min(l + 1, dim - 1);
        const float frac = vc - (float)l;
        float wlo = 1.0f - frac;
        float whi = frac;
        if (!valid) { wlo = 0.0f; whi = 0.0f; }
        const int mul = axis ? 1 : W;
        s_wlo[axis][i] = wlo;
        s_whi[axis][i] = whi;
        s_olo[axis][i] = l * mul;
        s_ohi[axis][i] = h * mul;
    }
    __syncthreads();

    const int b = (int)rb;
    const float* __restrict__ base = fp + (size_t)(b * CCH + t) * (size_t)(H * W);
    float* __restrict__ obase = out + ((size_t)k * CCH + t) * (OUT * OUT);

    for (int oh = 0; oh < OUT; ++oh) {
        const int sy0 = oh * 2;
        const float hy0 = s_wlo[0][sy0],   ly0 = s_whi[0][sy0];
        const float hy1 = s_wlo[0][sy0+1], ly1 = s_whi[0][sy0+1];
        const int oyl0 = s_olo[0][sy0],   oyh0 = s_ohi[0][sy0];
        const int oyl1 = s_olo[0][sy0+1], oyh1 = s_ohi[0][sy0+1];
        #pragma unroll
        for (int ow = 0; ow < OUT; ++ow) {
            float acc = 0.0f;
            #pragma unroll
            for (int dx = 0; dx < 2; ++dx) {
                const int sx = ow * 2 + dx;
                const float hx = s_wlo[1][sx];
                const float lx = s_whi[1][sx];
                const int oxl = s_olo[1][sx];
                const int oxh = s_ohi[1][sx];
                acc += hy0 * (hx * base[oyl0 + oxl] + lx * base[oyl0 + oxh])
                     + ly0 * (hx * base[oyh0 + oxl] + lx * base[oyh0 + oxh])
                     + hy1 * (hx * base[oyl1 + oxl] + lx * base[oyl1 + oxh])
                     + ly1 * (hx * base[oyh1 + oxl] + lx * base[oyh1 + oxh]);
            }
            obase[oh * OUT + ow] = acc * 0.25f;
        }
    }
}

extern "C" void kernel_launch(void* const* d_in, const int* in_sizes, int n_in,
                              void* d_out, int out_size, void* d_ws, size_t ws_size,
                              hipStream_t stream) {
    const float* f0   = (const float*)d_in[0];
    const float* f1   = (const float*)d_in[1];
    const float* f2   = (const float*)d_in[2];
    const float* f3   = (const float*)d_in[3];
    const float* rois = (const float*)d_in[4];
    float* out = (float*)d_out;

    const size_t need_bytes = (US0 + US1 + US2 + US3) * sizeof(unsigned short);
    if (ws_size >= need_bytes) {
        unsigned short* ws0 = (unsigned short*)d_ws;
        unsigned short* ws1 = ws0 + US0;
        unsigned short* ws2 = ws1 + US1;
        unsigned short* ws3 = ws2 + US2;
        transpose_bf16<<<T0 + T1 + T2 + T3, 256, 0, stream>>>(
            f0, f1, f2, f3, ws0, ws1, ws2, ws3);
        roi_gather_bf16<<<NUM_ROIS, 256, 0, stream>>>(ws0, ws1, ws2, ws3, rois, out);
    } else {
        roi_extract_direct<<<NUM_ROIS, 256, 0, stream>>>(f0, f1, f2, f3, rois, out);
    }
}

// Round 6
// 90.525 us; speedup vs baseline: 1.1373x; 1.1373x over previous
//
#include <hip/hip_runtime.h>

typedef unsigned int uint32;

namespace {
constexpr int CCH = 256;   // channels
constexpr int OUT = 7;     // output size
constexpr int S   = 14;    // OUT * SAMPLE_NUM
constexpr int NUM_ROIS = 1024;

constexpr int H0 = 200, W0 = 304;
constexpr int H1 = 100, W1 = 152;
constexpr int H2 = 50,  W2 = 76;
constexpr int H3 = 25,  W3 = 38;

constexpr int HW0 = H0 * W0;   // 60800
constexpr int HW1 = H1 * W1;   // 15200
constexpr int HW2 = H2 * W2;   // 3800
constexpr int HW3 = H3 * W3;   // 950

// transposed bf16 NHWC level sizes (in ushorts)
constexpr size_t US0 = (size_t)2 * HW0 * CCH;
constexpr size_t US1 = (size_t)2 * HW1 * CCH;
constexpr size_t US2 = (size_t)2 * HW2 * CCH;
constexpr size_t US3 = (size_t)2 * HW3 * CCH;

// hw-tiles of 128 per (b, c-half): grid chunk = 4 * ceil(HW/128)
constexpr int TPB0 = (HW0 + 127) / 128;   // 475 (exact)
constexpr int TPB1 = (HW1 + 127) / 128;   // 119
constexpr int TPB2 = (HW2 + 127) / 128;   // 30
constexpr int TPB3 = (HW3 + 127) / 128;   // 8
constexpr int G0 = 4 * TPB0;              // 1900
constexpr int G1 = 4 * TPB1;              // 476
constexpr int G2 = 4 * TPB2;              // 120
constexpr int G3 = 4 * TPB3;              // 32

constexpr int LROW = 70;   // LDS row stride in words (64 c-pairs + pad, even)
}

__device__ __forceinline__ unsigned short f2bf(float f) {
    uint32 u = __float_as_uint(f);
    u += 0x7fffu + ((u >> 16) & 1u);          // round-to-nearest-even
    return (unsigned short)(u >> 16);
}
__device__ __forceinline__ float blo(uint32 u) { return __uint_as_float(u << 16); }
__device__ __forceinline__ float bhi(uint32 u) { return __uint_as_float(u & 0xffff0000u); }

// ---- fused NCHW fp32 -> NHWC bf16 transpose, hw-contiguous 128x128 tiles ---
// Tile: 128 contiguous hw positions x 128 channels (one c-half). Per-channel
// global read runs = 512B (the DRAM-efficient pattern the gather proved out).
// LDS: [hw][c-pair] packed b32, row stride 70 words. Output: per hw, 256B
// contiguous c-run.
__global__ __launch_bounds__(256) void transpose_bf16_v3(
    const float* __restrict__ f0, const float* __restrict__ f1,
    const float* __restrict__ f2, const float* __restrict__ f3,
    unsigned short* __restrict__ o0, unsigned short* __restrict__ o1,
    unsigned short* __restrict__ o2, unsigned short* __restrict__ o3)
{
    __shared__ uint32 lds[128 * LROW];
    int r = blockIdx.x;
    const float* in; unsigned short* op; int HW, TPB;
    if (r < G0)                {                 in = f0; op = o0; HW = HW0; TPB = TPB0; }
    else if (r < G0+G1)        { r -= G0;        in = f1; op = o1; HW = HW1; TPB = TPB1; }
    else if (r < G0+G1+G2)     { r -= G0+G1;     in = f2; op = o2; HW = HW2; TPB = TPB2; }
    else                       { r -= G0+G1+G2;  in = f3; op = o3; HW = HW3; TPB = TPB3; }
    const int b    = r / (2 * TPB);
    int rest = r - b * 2 * TPB;
    const int half = rest / TPB;
    const int tile = rest - half * TPB;
    const int hw0  = tile * 128;
    const int n    = min(128, HW - hw0);        // valid hw in this tile
    const int t    = threadIdx.x;

    const int hq = t & 15;     // hw quad index (x4 -> 64 per h2 half)
    const int cp = t >> 4;     // 0..15 channel-pair group

    const float* src = in + (size_t)(b * CCH + half * 128) * HW + hw0;
    const bool aligned = ((HW & 3) == 0);       // level 3 (950) is not

    // ---- Phase A: load 16 float4 (8 c-pairs x 2 hw-halves), stage in regs --
    float4 va[8], vb[8];
    #pragma unroll
    for (int h2 = 0; h2 < 2; ++h2) {
        #pragma unroll
        for (int i = 0; i < 4; ++i) {
            const int idx = h2 * 4 + i;
            const int c   = 2 * (cp + 16 * i);
            const int hwq = 4 * hq + 64 * h2;
            const float* p = src + (size_t)c * HW + hwq;
            const float* q = p + HW;
            if (aligned && hwq + 3 < n) {
                va[idx] = *reinterpret_cast<const float4*>(p);
                vb[idx] = *reinterpret_cast<const float4*>(q);
            } else {
                float4 a = make_float4(0.f,0.f,0.f,0.f);
                float4 bb = make_float4(0.f,0.f,0.f,0.f);
                if (hwq + 0 < n) { a.x = p[0]; bb.x = q[0]; }
                if (hwq + 1 < n) { a.y = p[1]; bb.y = q[1]; }
                if (hwq + 2 < n) { a.z = p[2]; bb.z = q[2]; }
                if (hwq + 3 < n) { a.w = p[3]; bb.w = q[3]; }
                va[idx] = a; vb[idx] = bb;
            }
        }
    }
    // ---- convert + LDS writes (b32, c-pair packed) ----
    #pragma unroll
    for (int h2 = 0; h2 < 2; ++h2) {
        #pragma unroll
        for (int i = 0; i < 4; ++i) {
            const int idx = h2 * 4 + i;
            const int col = cp + 16 * i;
            const int hwr = 4 * hq + 64 * h2;
            const uint32 u0 = (uint32)f2bf(va[idx].x) | ((uint32)f2bf(vb[idx].x) << 16);
            const uint32 u1 = (uint32)f2bf(va[idx].y) | ((uint32)f2bf(vb[idx].y) << 16);
            const uint32 u2 = (uint32)f2bf(va[idx].z) | ((uint32)f2bf(vb[idx].z) << 16);
            const uint32 u3 = (uint32)f2bf(va[idx].w) | ((uint32)f2bf(vb[idx].w) << 16);
            lds[(hwr + 0) * LROW + col] = u0;
            lds[(hwr + 1) * LROW + col] = u1;
            lds[(hwr + 2) * LROW + col] = u2;
            lds[(hwr + 3) * LROW + col] = u3;
        }
    }
    __syncthreads();

    // ---- Phase B: uint4 (8 ch) coalesced stores ----
    {
        const int cg = t & 15;         // 16B chunk: channels 8cg..8cg+7 of half
        const int j0 = t >> 4;         // 0..15
        #pragma unroll
        for (int it = 0; it < 8; ++it) {
            const int j = j0 + 16 * it;
            const uint2 ra = *reinterpret_cast<const uint2*>(&lds[j * LROW + 4 * cg]);
            const uint2 rb = *reinterpret_cast<const uint2*>(&lds[j * LROW + 4 * cg + 2]);
            if (j < n) {
                uint4 v = make_uint4(ra.x, ra.y, rb.x, rb.y);
                *reinterpret_cast<uint4*>(
                    op + ((size_t)b * HW + hw0 + j) * CCH + half * 128 + 8 * cg) = v;
            }
        }
    }
}

// ---------------- gather from NHWC bf16 -------------------------------------
__global__ __launch_bounds__(256) void roi_gather_bf16(
    const unsigned short* __restrict__ w0, const unsigned short* __restrict__ w1,
    const unsigned short* __restrict__ w2, const unsigned short* __restrict__ w3,
    const float* __restrict__ rois, float* __restrict__ out)
{
    const int k = blockIdx.x;
    const int t = threadIdx.x;

    __shared__ float s_wlo[2][S];
    __shared__ float s_whi[2][S];
    __shared__ int   s_olo[2][S];   // offsets in uint2 units (y: W*64, x: 64)
    __shared__ int   s_ohi[2][S];
    __shared__ __align__(16) float s_out[25 * 260];

    const float rb  = rois[k*5+0];
    const float rx1 = rois[k*5+1];
    const float ry1 = rois[k*5+2];
    const float rx2 = rois[k*5+3];
    const float ry2 = rois[k*5+4];

    const float sc = sqrtf((rx2 - rx1 + 1.0f) * (ry2 - ry1 + 1.0f));
    int lvl = (int)floorf(log2f(sc * (1.0f/56.0f) + 1e-6f));
    lvl = lvl < 0 ? 0 : (lvl > 3 ? 3 : lvl);

    const unsigned short* fp; int H, W; float sp;
    if (lvl == 0)      { fp = w0; H = H0; W = W0; sp = 0.25f;    }
    else if (lvl == 1) { fp = w1; H = H1; W = W1; sp = 0.125f;   }
    else if (lvl == 2) { fp = w2; H = H2; W = W2; sp = 0.0625f;  }
    else               { fp = w3; H = H3; W = W3; sp = 0.03125f; }

    if (t < 2*S) {
        const int axis = (t >= S) ? 1 : 0;     // 0=y, 1=x
        const int i = axis ? (t - S) : t;
        const float lo = (axis ? rx1 : ry1) * sp;
        const float hi = (axis ? rx2 : ry2) * sp;
        const int dim  = axis ? W : H;
        const float len = fmaxf(hi - lo, 1.0f);
        const float bin = len * (1.0f / (float)S);
        const float v = lo + ((float)i + 0.5f) * bin;
        const bool valid = (v >= -1.0f) && (v <= (float)dim);
        float vc = fmaxf(v, 0.0f);
        int l = (int)floorf(vc);
        if (l >= dim - 1) { vc = (float)(dim - 1); l = dim - 1; }
        const int h = min(l + 1, dim - 1);
        const float frac = vc - (float)l;
        float wlo = 1.0f - frac;
        float whi = frac;
        if (!valid) { wlo = 0.0f; whi = 0.0f; }
        const int mul = axis ? 64 : W * 64;    // uint2 units
        s_wlo[axis][i] = wlo;
        s_whi[axis][i] = whi;
        s_olo[axis][i] = l * mul;
        s_ohi[axis][i] = h * mul;
    }
    __syncthreads();

    const int b = (int)rb;
    const int lane = t & 63;
    const int wv   = t >> 6;
    const uint2* __restrict__ base =
        reinterpret_cast<const uint2*>(fp) + (size_t)b * H * W * 64 + lane;
    float* __restrict__ ob = out + (size_t)k * CCH * (OUT * OUT);

    #pragma unroll
    for (int hf = 0; hf < 2; ++hf) {
        const int bb = hf ? 25 : 0;
        const int ne = hf ? 24 : 25;

        for (int bl = wv; bl < ne; bl += 4) {
            const int bin = bb + bl;
            const int oh = bin / 7;
            const int ow = bin - oh * 7;
            const int sy0 = oh * 2, sx0 = ow * 2;
            float a0 = 0.f, a1 = 0.f, a2 = 0.f, a3 = 0.f;
            #pragma unroll
            for (int dy = 0; dy < 2; ++dy) {
                const float hy = s_wlo[0][sy0 + dy];
                const float ly = s_whi[0][sy0 + dy];
                const int oyl = s_olo[0][sy0 + dy];
                const int oyh = s_ohi[0][sy0 + dy];
                #pragma unroll
                for (int dx = 0; dx < 2; ++dx) {
                    const float hx = s_wlo[1][sx0 + dx];
                    const float lx = s_whi[1][sx0 + dx];
                    const int oxl = s_olo[1][sx0 + dx];
                    const int oxh = s_ohi[1][sx0 + dx];
                    const uint2 qll = base[oyl + oxl];
                    const uint2 qlh = base[oyl + oxh];
                    const uint2 qhl = base[oyh + oxl];
                    const uint2 qhh = base[oyh + oxh];
                    const float wll = hy * hx, wlh = hy * lx;
                    const float whl = ly * hx, whh = ly * lx;
                    a0 += wll*blo(qll.x) + wlh*blo(qlh.x) + whl*blo(qhl.x) + whh*blo(qhh.x);
                    a1 += wll*bhi(qll.x) + wlh*bhi(qlh.x) + whl*bhi(qhl.x) + whh*bhi(qhh.x);
                    a2 += wll*blo(qll.y) + wlh*blo(qlh.y) + whl*blo(qhl.y) + whh*blo(qhh.y);
                    a3 += wll*bhi(qll.y) + wlh*bhi(qlh.y) + whl*bhi(qhl.y) + whh*bhi(qhh.y);
                }
            }
            float4 res = make_float4(a0*0.25f, a1*0.25f, a2*0.25f, a3*0.25f);
            *reinterpret_cast<float4*>(&s_out[bl * 260 + 4 * lane]) = res;
        }
        __syncthreads();

        #pragma unroll 1
        for (int j = 0; j < ne; ++j) {
            const int f = t + j * 256;
            const int c = f / ne;
            const int bl = f - c * ne;
            ob[c * (OUT*OUT) + bb + bl] = s_out[bl * 260 + c];
        }
        __syncthreads();
    }
}

// ---------------- fallback (direct NCHW fp32) if ws too small ---------------
__global__ __launch_bounds__(256) void roi_extract_direct(
    const float* __restrict__ f0, const float* __restrict__ f1,
    const float* __restrict__ f2, const float* __restrict__ f3,
    const float* __restrict__ rois, float* __restrict__ out)
{
    const int k = blockIdx.x;
    const int t = threadIdx.x;

    __shared__ float s_wlo[2][S];
    __shared__ float s_whi[2][S];
    __shared__ int   s_olo[2][S];
    __shared__ int   s_ohi[2][S];

    const float rb  = rois[k*5+0];
    const float rx1 = rois[k*5+1];
    const float ry1 = rois[k*5+2];
    const float rx2 = rois[k*5+3];
    const float ry2 = rois[k*5+4];

    const float sc = sqrtf((rx2 - rx1 + 1.0f) * (ry2 - ry1 + 1.0f));
    int lvl = (int)floorf(log2f(sc * (1.0f/56.0f) + 1e-6f));
    lvl = lvl < 0 ? 0 : (lvl > 3 ? 3 : lvl);

    const float* fp; int H, W; float sp;
    if (lvl == 0)      { fp = f0; H = H0; W = W0; sp = 0.25f;    }
    else if (lvl == 1) { fp = f1; H = H1; W = W1; sp = 0.125f;   }
    else if (lvl == 2) { fp = f2; H = H2; W = W2; sp = 0.0625f;  }
    else               { fp = f3; H = H3; W = W3; sp = 0.03125f; }

    if (t < 2*S) {
        const int axis = (t >= S) ? 1 : 0;
        const int i = axis ? (t - S) : t;
        const float lo = (axis ? rx1 : ry1) * sp;
        const float hi = (axis ? rx2 : ry2) * sp;
        const int dim  = axis ? W : H;
        const float len = fmaxf(hi - lo, 1.0f);
        const float bin = len * (1.0f / (float)S);
        const float v = lo + ((float)i + 0.5f) * bin;
        const bool valid = (v >= -1.0f) && (v <= (float)dim);
        float vc = fmaxf(v, 0.0f);
        int l = (int)floorf(vc);
        if (l >= dim - 1) { vc = (float)(dim - 1); l = dim - 1; }
        const int h = min(l + 1, dim - 1);
        const float frac = vc - (float)l;
        float wlo = 1.0f - frac;
        float whi = frac;
        if (!valid) { wlo = 0.0f; whi = 0.0f; }
        const int mul = axis ? 1 : W;
        s_wlo[axis][i] = wlo;
        s_whi[axis][i] = whi;
        s_olo[axis][i] = l * mul;
        s_ohi[axis][i] = h * mul;
    }
    __syncthreads();

    const int b = (int)rb;
    const float* __restrict__ base = fp + (size_t)(b * CCH + t) * (size_t)(H * W);
    float* __restrict__ obase = out + ((size_t)k * CCH + t) * (OUT * OUT);

    for (int oh = 0; oh < OUT; ++oh) {
        const int sy0 = oh * 2;
        const float hy0 = s_wlo[0][sy0],   ly0 = s_whi[0][sy0];
        const float hy1 = s_wlo[0][sy0+1], ly1 = s_whi[0][sy0+1];
        const int oyl0 = s_olo[0][sy0],   oyh0 = s_ohi[0][sy0];
        const int oyl1 = s_olo[0][sy0+1], oyh1 = s_ohi[0][sy0+1];
        #pragma unroll
        for (int ow = 0; ow < OUT; ++ow) {
            float acc = 0.0f;
            #pragma unroll
            for (int dx = 0; dx < 2; ++dx) {
                const int sx = ow * 2 + dx;
                const float hx = s_wlo[1][sx];
                const float lx = s_whi[1][sx];
                const int oxl = s_olo[1][sx];
                const int oxh = s_ohi[1][sx];
                acc += hy0 * (hx * base[oyl0 + oxl] + lx * base[oyl0 + oxh])
                     + ly0 * (hx * base[oyh0 + oxl] + lx * base[oyh0 + oxh])
                     + hy1 * (hx * base[oyl1 + oxl] + lx * base[oyl1 + oxh])
                     + ly1 * (hx * base[oyh1 + oxl] + lx * base[oyh1 + oxh]);
            }
            obase[oh * OUT + ow] = acc * 0.25f;
        }
    }
}

extern "C" void kernel_launch(void* const* d_in, const int* in_sizes, int n_in,
                              void* d_out, int out_size, void* d_ws, size_t ws_size,
                              hipStream_t stream) {
    const float* f0   = (const float*)d_in[0];
    const float* f1   = (const float*)d_in[1];
    const float* f2   = (const float*)d_in[2];
    const float* f3   = (const float*)d_in[3];
    const float* rois = (const float*)d_in[4];
    float* out = (float*)d_out;

    const size_t need_bytes = (US0 + US1 + US2 + US3) * sizeof(unsigned short);
    if (ws_size >= need_bytes) {
        unsigned short* ws0 = (unsigned short*)d_ws;
        unsigned short* ws1 = ws0 + US0;
        unsigned short* ws2 = ws1 + US1;
        unsigned short* ws3 = ws2 + US2;
        transpose_bf16_v3<<<G0 + G1 + G2 + G3, 256, 0, stream>>>(
            f0, f1, f2, f3, ws0, ws1, ws2, ws3);
        roi_gather_bf16<<<NUM_ROIS, 256, 0, stream>>>(ws0, ws1, ws2, ws3, rois, out);
    } else {
        roi_extract_direct<<<NUM_ROIS, 256, 0, stream>>>(f0, f1, f2, f3, rois, out);
    }
}